// Round 2
// baseline (254.287 us; speedup 1.0000x reference)
//
#include <hip/hip_runtime.h>

#define NT 256
#define W 56
#define HW 3136          // 56*56
#define PW 58
#define PAD_SZ (58*58)   // 3364
#define KSEL 30
#define PER 13           // ceil(3136/256)
#define EQCAP 128

__global__ __launch_bounds__(NT, 4) void topk_spatial_kernel(
    const float* __restrict__ x,
    const float* __restrict__ wgt,
    const float* __restrict__ bias,
    float* __restrict__ out,
    int C)
{
    __shared__ float xs[PAD_SZ];
    __shared__ __align__(16) int hist[256];
    __shared__ unsigned int keepw[HW / 32];   // 98 words = 3136 bits
    __shared__ int          eq_idx[EQCAP];
    __shared__ unsigned int eq_lo[EQCAP];
    __shared__ int s_B, s_Kr, s_eqcnt;

    const int tid = threadIdx.x;
    const int bc  = blockIdx.x;              // b*C + c
    const int ci  = bc % C;

    const float* xp = x   + (size_t)bc * HW;
    float*       op = out + (size_t)bc * HW;

    // channel weights in double (uniform -> scalar loads)
    const float* wp = wgt + (size_t)ci * 9;
    const double w00 = wp[0], w01 = wp[1], w02 = wp[2];
    const double w10 = wp[3], w11 = wp[4], w12 = wp[5];
    const double w20 = wp[6], w21 = wp[7], w22 = wp[8];
    const double bv  = bias[ci];

    // zero padded tile + keep bits
    for (int i = tid; i < PAD_SZ; i += NT) xs[i] = 0.0f;
    for (int i = tid; i < HW / 32; i += NT) keepw[i] = 0u;
    if (tid == 0) s_eqcnt = 0;
    __syncthreads();

    // load interior as float4 (56 % 4 == 0 -> each quad within one row)
    for (int t = tid; t < HW / 4; t += NT) {
        float4 v = reinterpret_cast<const float4*>(xp)[t];
        int i = t * 4;
        int y = i / W;
        int p = (y + 1) * PW + (i - y * W) + 1;
        xs[p]     = v.x;
        xs[p + 1] = v.y;
        xs[p + 2] = v.z;
        xs[p + 3] = v.w;
    }
    __syncthreads();

    // conv in f64 -> order-preserving 64-bit keys (hi/lo 32-bit halves in regs)
    unsigned int khi[PER], klo[PER];
    #pragma unroll
    for (int k = 0; k < PER; ++k) {
        const int i = tid + k * NT;
        unsigned long long key = 0ull;       // invalid lanes: smallest key
        if (i < HW) {
            const int y = i / W;
            const int p = (y + 1) * PW + (i - y * W) + 1;
            double s = bv;
            s = fma(w00, (double)xs[p - PW - 1], s);
            s = fma(w01, (double)xs[p - PW    ], s);
            s = fma(w02, (double)xs[p - PW + 1], s);
            s = fma(w10, (double)xs[p - 1],      s);
            s = fma(w11, (double)xs[p],          s);
            s = fma(w12, (double)xs[p + 1],      s);
            s = fma(w20, (double)xs[p + PW - 1], s);
            s = fma(w21, (double)xs[p + PW    ], s);
            s = fma(w22, (double)xs[p + PW + 1], s);
            const unsigned long long b = (unsigned long long)__double_as_longlong(s);
            key = ((long long)b < 0) ? ~b : (b | 0x8000000000000000ull);
        }
        khi[k] = (unsigned int)(key >> 32);
        klo[k] = (unsigned int)key;
    }

    // 4-level radix select on the HIGH 32 bits of the key
    unsigned int prefix = 0u;
    int Kr = KSEL;
    #pragma unroll
    for (int lvl = 0; lvl < 4; ++lvl) {
        const int shift = 24 - lvl * 8;

        hist[tid] = 0;
        __syncthreads();

        #pragma unroll
        for (int k = 0; k < PER; ++k) {
            const int i = tid + k * NT;
            if (i < HW) {
                const unsigned int uk = khi[k];
                bool cand;
                if (lvl == 0) cand = true;
                else          cand = ((uk >> (shift + 8)) == (prefix >> (shift + 8)));
                if (cand) atomicAdd(&hist[(uk >> shift) & 255], 1);
            }
        }
        __syncthreads();

        // wave 0: suffix scan over 256 bins + find crossing bin
        if (tid < 64) {
            const int4 hv = *reinterpret_cast<const int4*>(&hist[4 * tid]);
            const int s3 = hv.w;
            const int s2 = hv.z + s3;
            const int s1 = hv.y + s2;
            const int s0 = hv.x + s1;
            int incl = s0;
            #pragma unroll
            for (int d = 1; d < 64; d <<= 1) {
                const int v = __shfl_down(incl, d);
                if (tid + d < 64) incl += v;
            }
            const int above = incl - s0;     // sum over lanes > tid
            const int ssv[5] = { above + s0, above + s1, above + s2, above + s3, above };
            #pragma unroll
            for (int j = 0; j < 4; ++j) {
                const int cur = ssv[j], nxt = ssv[j + 1];
                if (cur >= Kr && nxt < Kr) {
                    s_B  = 4 * tid + j;
                    s_Kr = Kr - nxt;
                }
            }
        }
        __syncthreads();
        prefix |= ((unsigned int)s_B) << shift;
        Kr = s_Kr;
    }
    // prefix == hi-32 of the K-th largest key; Kr == #elements with khi==prefix to keep

    // collect elements with khi == prefix (rare: usually exactly Kr of them)
    #pragma unroll
    for (int k = 0; k < PER; ++k) {
        const int i = tid + k * NT;
        if (i < HW && khi[k] == prefix) {
            const int slot = atomicAdd(&s_eqcnt, 1);
            if (slot < EQCAP) { eq_idx[slot] = i; eq_lo[slot] = klo[k]; }
        }
    }
    __syncthreads();

    // thread 0: pick Kr winners among equals by (klo desc, index asc)
    if (tid == 0) {
        const int E = (s_eqcnt < EQCAP) ? s_eqcnt : EQCAP;
        for (int r = 0; r < Kr; ++r) {
            int best = -1, bi = 0x7fffffff;
            unsigned int bl = 0u;
            for (int e = 0; e < E; ++e) {
                const int ix = eq_idx[e];
                if (ix < 0) continue;
                const unsigned int l = eq_lo[e];
                if (best < 0 || l > bl || (l == bl && ix < bi)) { best = e; bl = l; bi = ix; }
            }
            if (best >= 0) {
                eq_idx[best] = -1;
                keepw[bi >> 5] |= (1u << (bi & 31));
            }
        }
    }
    __syncthreads();

    // write output: keep = khi > prefix, or chosen equal
    #pragma unroll
    for (int k = 0; k < PER; ++k) {
        const int i = tid + k * NT;
        if (i < HW) {
            const bool keep = (khi[k] > prefix) ||
                              ((keepw[i >> 5] >> (i & 31)) & 1u);
            const int y = i / W;
            const int p = (y + 1) * PW + (i - y * W) + 1;
            op[i] = keep ? xs[p] : 0.0f;
        }
    }
}

extern "C" void kernel_launch(void* const* d_in, const int* in_sizes, int n_in,
                              void* d_out, int out_size, void* d_ws, size_t ws_size,
                              hipStream_t stream) {
    const float* x  = (const float*)d_in[0];
    const float* w  = (const float*)d_in[1];
    const float* b  = (const float*)d_in[2];
    float* out      = (float*)d_out;

    const int C  = in_sizes[2];            // 384
    const int BC = in_sizes[0] / HW;       // b*c = 12288

    topk_spatial_kernel<<<BC, NT, 0, stream>>>(x, w, b, out, C);
}

// Round 3
// 174.974 us; speedup vs baseline: 1.4533x; 1.4533x over previous
//
#include <hip/hip_runtime.h>

#define NT 256
#define W 56
#define HW 3136          // 56*56
#define PW 58
#define PAD_SZ (PW*PW)   // 3364
#define KSEL 30
#define PER 13           // ceil(3136/256)
#define CAP 256

__global__ __launch_bounds__(NT, 4) void topk_spatial_kernel(
    const float* __restrict__ x,
    const float* __restrict__ wgt,
    const float* __restrict__ bias,
    float* __restrict__ out,
    int C)
{
    __shared__ float xs[PAD_SZ];
    __shared__ unsigned int smax[NT];
    __shared__ unsigned int c_hi[CAP];
    __shared__ unsigned int c_lo[CAP];
    __shared__ int          c_idx[CAP];
    __shared__ unsigned int keepw[HW / 32];   // 98 words = 3136 bits
    __shared__ unsigned int s_T;
    __shared__ int s_cnt;

    const int tid = threadIdx.x;
    const int bc  = blockIdx.x;              // b*C + c
    const int ci  = bc % C;

    const float* xp = x   + (size_t)bc * HW;
    float*       op = out + (size_t)bc * HW;

    // channel weights in double (uniform -> scalar loads)
    const float* wp = wgt + (size_t)ci * 9;
    const double w00 = wp[0], w01 = wp[1], w02 = wp[2];
    const double w10 = wp[3], w11 = wp[4], w12 = wp[5];
    const double w20 = wp[6], w21 = wp[7], w22 = wp[8];
    const double bv  = bias[ci];

    // init: zero ONLY the perimeter of the padded tile (interior fully
    // overwritten by the load), keep bits, candidate counter
    if (tid < 228) {
        int p;
        if (tid < 58)       p = tid;                         // top row
        else if (tid < 116) p = 57 * PW + (tid - 58);        // bottom row
        else if (tid < 172) p = (tid - 115) * PW;            // left col, rows 1..56
        else                p = (tid - 171) * PW + 57;       // right col, rows 1..56
        xs[p] = 0.0f;
    }
    if (tid < HW / 32) keepw[tid] = 0u;
    if (tid == 255) s_cnt = 0;

    // load interior as float4 (56 % 4 == 0 -> each quad within one row)
    for (int t = tid; t < HW / 4; t += NT) {
        float4 v = reinterpret_cast<const float4*>(xp)[t];
        int i = t * 4;
        int y = i / W;
        int p = (y + 1) * PW + (i - y * W) + 1;
        xs[p]     = v.x;
        xs[p + 1] = v.y;
        xs[p + 2] = v.z;
        xs[p + 3] = v.w;
    }
    __syncthreads();                                         // B1

    // conv in f64 -> order-preserving 64-bit keys (hi/lo halves in regs)
    unsigned int khi[PER], klo[PER];
    unsigned int mx = 0u;
    #pragma unroll
    for (int k = 0; k < PER; ++k) {
        const int i = tid + k * NT;
        unsigned long long key = 0ull;       // invalid lanes: smallest key
        if (i < HW) {
            const int y = i / W;
            const int p = (y + 1) * PW + (i - y * W) + 1;
            double s = bv;
            s = fma(w00, (double)xs[p - PW - 1], s);
            s = fma(w01, (double)xs[p - PW    ], s);
            s = fma(w02, (double)xs[p - PW + 1], s);
            s = fma(w10, (double)xs[p - 1],      s);
            s = fma(w11, (double)xs[p],          s);
            s = fma(w12, (double)xs[p + 1],      s);
            s = fma(w20, (double)xs[p + PW - 1], s);
            s = fma(w21, (double)xs[p + PW    ], s);
            s = fma(w22, (double)xs[p + PW + 1], s);
            const unsigned long long b = (unsigned long long)__double_as_longlong(s);
            key = ((long long)b < 0) ? ~b : (b | 0x8000000000000000ull);
        }
        khi[k] = (unsigned int)(key >> 32);
        klo[k] = (unsigned int)key;
        mx = (khi[k] > mx) ? khi[k] : mx;
    }

    smax[tid] = mx;
    __syncthreads();                                         // B2

    // wave 0: binary search for threshold T with #(maxima >= T) in [30, 48].
    // Since each thread-max >= T contributes >= 1 element >= T, the true
    // top-30 elements all satisfy khi >= T.
    if (tid < 64) {
        const unsigned int m0 = smax[tid];
        const unsigned int m1 = smax[tid + 64];
        const unsigned int m2 = smax[tid + 128];
        const unsigned int m3 = smax[tid + 192];
        unsigned int lo = 0u, hi = 0xFFFFFFFFu;  // cnt(>=lo) >= 30 > cnt(>=hi)
        for (int it = 0; it < 34; ++it) {
            if (hi - lo <= 1u) break;
            const unsigned int mid = lo + ((hi - lo) >> 1);
            int c = (m0 >= mid) + (m1 >= mid) + (m2 >= mid) + (m3 >= mid);
            #pragma unroll
            for (int d = 1; d < 64; d <<= 1) c += __shfl_xor(c, d);
            if (c >= KSEL) { lo = mid; if (c <= 48) break; }
            else hi = mid;
        }
        if (tid == 0) s_T = lo;
    }
    __syncthreads();                                         // B3

    // gather candidates (khi >= T) with full keys
    const unsigned int T = s_T;
    #pragma unroll
    for (int k = 0; k < PER; ++k) {
        const int i = tid + k * NT;
        if (i < HW && khi[k] >= T) {
            const int slot = atomicAdd(&s_cnt, 1);
            if (slot < CAP) {
                c_hi[slot]  = khi[k];
                c_lo[slot]  = klo[k];
                c_idx[slot] = i;
            }
        }
    }
    __syncthreads();                                         // B4

    // exact rank among candidates: (khi desc, klo desc, idx asc); keep rank<K
    const int E = (s_cnt < CAP) ? s_cnt : CAP;
    if (tid < E) {
        const unsigned int eh = c_hi[tid];
        const unsigned int el = c_lo[tid];
        const int          ei = c_idx[tid];
        int rank = 0;
        for (int j = 0; j < E; ++j) {
            const unsigned int jh = c_hi[j];
            const unsigned int jl = c_lo[j];
            const int          ji = c_idx[j];
            const bool g = (jh > eh) ||
                           (jh == eh && (jl > el || (jl == el && ji < ei)));
            rank += g;
        }
        if (rank < KSEL) atomicOr(&keepw[ei >> 5], 1u << (ei & 31));
    }
    __syncthreads();                                         // B5

    // write output as float4: keep bits x LDS tile
    for (int t = tid; t < HW / 4; t += NT) {
        const int i = 4 * t;
        const int y = i / W;
        const int p = (y + 1) * PW + (i - y * W) + 1;
        const unsigned int wbits = keepw[i >> 5] >> (i & 31);
        float4 v;
        v.x = (wbits & 1u) ? xs[p]     : 0.0f;
        v.y = (wbits & 2u) ? xs[p + 1] : 0.0f;
        v.z = (wbits & 4u) ? xs[p + 2] : 0.0f;
        v.w = (wbits & 8u) ? xs[p + 3] : 0.0f;
        reinterpret_cast<float4*>(op)[t] = v;
    }
}

extern "C" void kernel_launch(void* const* d_in, const int* in_sizes, int n_in,
                              void* d_out, int out_size, void* d_ws, size_t ws_size,
                              hipStream_t stream) {
    const float* x  = (const float*)d_in[0];
    const float* w  = (const float*)d_in[1];
    const float* b  = (const float*)d_in[2];
    float* out      = (float*)d_out;

    const int C  = in_sizes[2];            // 384
    const int BC = in_sizes[0] / HW;       // b*c = 12288

    topk_spatial_kernel<<<BC, NT, 0, stream>>>(x, w, b, out, C);
}

// Round 4
// 154.572 us; speedup vs baseline: 1.6451x; 1.1320x over previous
//
#include <hip/hip_runtime.h>

#define NT 256
#define W 56
#define HW 3136          // 56*56
#define PW 58
#define PAD_SZ (PW*PW)   // 3364
#define KSEL 30
#define PER 13           // ceil(3136/256)
#define CAP 160

__global__ __launch_bounds__(NT, 4) void topk_spatial_kernel(
    const float* __restrict__ x,
    const float* __restrict__ wgt,
    const float* __restrict__ bias,
    float* __restrict__ out,
    int C)
{
    __shared__ float        xs[PAD_SZ];
    __shared__ unsigned int smax[NT];
    __shared__ int          c_idx[CAP];
    __shared__ double       c_sd[CAP];
    __shared__ unsigned int keepw[HW / 32];   // 98 words = 3136 bits
    __shared__ unsigned int s_T16;
    __shared__ int s_cnt;

    const int tid = threadIdx.x;
    const int bc  = blockIdx.x;              // b*C + c
    const int ci  = bc % C;

    const float* xp = x   + (size_t)bc * HW;
    float*       op = out + (size_t)bc * HW;

    // channel weights in f32 for the selection conv
    const float* wp = wgt + (size_t)ci * 9;
    const float w00 = wp[0], w01 = wp[1], w02 = wp[2];
    const float w10 = wp[3], w11 = wp[4], w12 = wp[5];
    const float w20 = wp[6], w21 = wp[7], w22 = wp[8];
    const float bv  = bias[ci];

    // init: zero ONLY the perimeter (interior fully overwritten), keep bits
    if (tid < 228) {
        int p;
        if (tid < 58)       p = tid;                         // top row
        else if (tid < 116) p = 57 * PW + (tid - 58);        // bottom row
        else if (tid < 172) p = (tid - 115) * PW;            // left col
        else                p = (tid - 171) * PW + 57;       // right col
        xs[p] = 0.0f;
    }
    if (tid < HW / 32) keepw[tid] = 0u;
    if (tid == 255) s_cnt = 0;

    // load interior as float4 (56 % 4 == 0 -> each quad within one row)
    for (int t = tid; t < HW / 4; t += NT) {
        float4 v = reinterpret_cast<const float4*>(xp)[t];
        int i = t * 4;
        int y = i / W;
        int p = (y + 1) * PW + (i - y * W) + 1;
        xs[p]     = v.x;
        xs[p + 1] = v.y;
        xs[p + 2] = v.z;
        xs[p + 3] = v.w;
    }
    __syncthreads();                                         // B1

    // f32 conv -> order-preserving 32-bit keys in regs; per-thread max
    unsigned int k32[PER];
    unsigned int mx = 0u;
    #pragma unroll
    for (int k = 0; k < PER; ++k) {
        const int i = tid + k * NT;
        unsigned int key = 0u;               // invalid lanes: smallest key
        if (i < HW) {
            const int y = i / W;
            const int p = (y + 1) * PW + (i - y * W) + 1;
            float s = bv;
            s = fmaf(w00, xs[p - PW - 1], s);
            s = fmaf(w01, xs[p - PW    ], s);
            s = fmaf(w02, xs[p - PW + 1], s);
            s = fmaf(w10, xs[p - 1],      s);
            s = fmaf(w11, xs[p],          s);
            s = fmaf(w12, xs[p + 1],      s);
            s = fmaf(w20, xs[p + PW - 1], s);
            s = fmaf(w21, xs[p + PW    ], s);
            s = fmaf(w22, xs[p + PW + 1], s);
            const unsigned int b = __float_as_uint(s);
            key = ((int)b < 0) ? ~b : (b | 0x80000000u);
        }
        k32[k] = key;
        mx = (key > mx) ? key : mx;
    }
    smax[tid] = mx;
    __syncthreads();                                         // B2

    // wave 0: 16-iter binary search on hi-16 key bits for a bin T16 with
    // #(thread-maxima >= T16) in [30, 48]; ballot+popcount reduction
    if (tid < 64) {
        const unsigned int m0 = smax[tid]       >> 16;
        const unsigned int m1 = smax[tid + 64]  >> 16;
        const unsigned int m2 = smax[tid + 128] >> 16;
        const unsigned int m3 = smax[tid + 192] >> 16;
        unsigned int lo = 0u, hi = 65536u;   // cnt(>=lo) >= 30 > cnt(>=hi)
        while (hi - lo > 1u) {
            const unsigned int mid = (lo + hi) >> 1;
            const int c = (m0 >= mid) + (m1 >= mid) + (m2 >= mid) + (m3 >= mid);
            const unsigned long long b0 = __ballot(c & 1);
            const unsigned long long b1 = __ballot(c & 2);
            const unsigned long long b2 = __ballot(c & 4);
            const int cnt = __popcll(b0) + 2 * __popcll(b1) + 4 * __popcll(b2);
            if (cnt >= KSEL) { lo = mid; if (cnt <= 48) break; }
            else hi = mid;
        }
        if (tid == 0) s_T16 = lo;
    }
    __syncthreads();                                         // B3

    // widen cut by absolute margin 1e-4 (>> 2*f32-conv-error) in float domain
    const unsigned int binkey = s_T16 << 16;
    const float Tf = (binkey & 0x80000000u)
                         ? __uint_as_float(binkey ^ 0x80000000u)
                         : __uint_as_float(~binkey);
    const float Tm = Tf - 1e-4f;
    const unsigned int tb    = __float_as_uint(Tm);
    const unsigned int TmKey = ((int)tb < 0) ? ~tb : (tb | 0x80000000u);

    // gather candidate indices
    #pragma unroll
    for (int k = 0; k < PER; ++k) {
        const int i = tid + k * NT;
        if (i < HW && k32[k] >= TmKey) {
            const int slot = atomicAdd(&s_cnt, 1);
            if (slot < CAP) c_idx[slot] = i;
        }
    }
    __syncthreads();                                         // B4

    // f64 recompute for candidates only (same fma order as the np-matching
    // round-2 kernel -> bit-identical ranking)
    const int E = (s_cnt < CAP) ? s_cnt : CAP;
    if (tid < E) {
        const int i = c_idx[tid];
        const int y = i / W;
        const int p = (y + 1) * PW + (i - y * W) + 1;
        double s = (double)bv;
        s = fma((double)w00, (double)xs[p - PW - 1], s);
        s = fma((double)w01, (double)xs[p - PW    ], s);
        s = fma((double)w02, (double)xs[p - PW + 1], s);
        s = fma((double)w10, (double)xs[p - 1],      s);
        s = fma((double)w11, (double)xs[p],          s);
        s = fma((double)w12, (double)xs[p + 1],      s);
        s = fma((double)w20, (double)xs[p + PW - 1], s);
        s = fma((double)w21, (double)xs[p + PW    ], s);
        s = fma((double)w22, (double)xs[p + PW + 1], s);
        c_sd[tid] = s;
    }
    __syncthreads();                                         // B5

    // exact rank among candidates: (s64 desc, idx asc); keep rank < K
    if (tid < E) {
        const double se = c_sd[tid];
        const int    ei = c_idx[tid];
        int rank = 0;
        for (int j = 0; j < E; ++j) {
            const double sj = c_sd[j];
            const int    ji = c_idx[j];
            rank += (sj > se) || (sj == se && ji < ei);
        }
        if (rank < KSEL) atomicOr(&keepw[ei >> 5], 1u << (ei & 31));
    }
    __syncthreads();                                         // B6

    // write output as float4: keep bits x LDS tile
    for (int t = tid; t < HW / 4; t += NT) {
        const int i = 4 * t;
        const int y = i / W;
        const int p = (y + 1) * PW + (i - y * W) + 1;
        const unsigned int wbits = keepw[i >> 5] >> (i & 31);
        float4 v;
        v.x = (wbits & 1u) ? xs[p]     : 0.0f;
        v.y = (wbits & 2u) ? xs[p + 1] : 0.0f;
        v.z = (wbits & 4u) ? xs[p + 2] : 0.0f;
        v.w = (wbits & 8u) ? xs[p + 3] : 0.0f;
        reinterpret_cast<float4*>(op)[t] = v;
    }
}

extern "C" void kernel_launch(void* const* d_in, const int* in_sizes, int n_in,
                              void* d_out, int out_size, void* d_ws, size_t ws_size,
                              hipStream_t stream) {
    const float* x  = (const float*)d_in[0];
    const float* w  = (const float*)d_in[1];
    const float* b  = (const float*)d_in[2];
    float* out      = (float*)d_out;

    const int C  = in_sizes[2];            // 384
    const int BC = in_sizes[0] / HW;       // b*c = 12288

    topk_spatial_kernel<<<BC, NT, 0, stream>>>(x, w, b, out, C);
}

// Round 5
// 112.853 us; speedup vs baseline: 2.2533x; 1.3697x over previous
//
#include <hip/hip_runtime.h>

#define NT 256
#define W 56
#define HW 3136            // 56*56
#define PW 60              // padded row stride (floats)
#define GUARD 64           // zero guard before row 0
#define PAD_SZ (GUARD + 58*PW)   // 64 + 3480 = 3544 floats
#define KSEL 30
#define NQ (HW/4)          // 784 quads of 4 horizontally-contiguous outputs
#define CAP 160

__global__ __launch_bounds__(NT, 4) void topk_spatial_kernel(
    const float* __restrict__ x,
    const float* __restrict__ wgt,
    const float* __restrict__ bias,
    float* __restrict__ out,
    int C)
{
    // layout: xs[GUARD + (y+1)*PW + xcol] = x(y, xcol); cols 56..59 zero,
    // LDS rows 0 and 57 zero, xs[0..GUARD-1] zero. Reading col -1 of row y
    // lands on row y-1's col 59 (zero); row -1 lands in the guard (zero).
    __shared__ float        xs[PAD_SZ];
    __shared__ unsigned int smax[NT];
    __shared__ int          c_idx[CAP];
    __shared__ double       c_sd[CAP];
    __shared__ unsigned int keepw[HW / 32];   // 98 words = 3136 bits
    __shared__ unsigned int s_T16;
    __shared__ int s_cnt;

    const int tid = threadIdx.x;
    const int bc  = blockIdx.x;              // b*C + c
    const int ci  = bc % C;

    const float* xp = x   + (size_t)bc * HW;
    float*       op = out + (size_t)bc * HW;

    const float* wpt = wgt + (size_t)ci * 9;
    const float w00 = wpt[0], w01 = wpt[1], w02 = wpt[2];
    const float w10 = wpt[3], w11 = wpt[4], w12 = wpt[5];
    const float w20 = wpt[6], w21 = wpt[7], w22 = wpt[8];
    const float bv  = bias[ci];

    // ---- zero init (disjoint regions, interior overwritten by staging) ----
    if (tid < GUARD) xs[tid] = 0.0f;                         // guard
    if (tid < PW) {
        xs[GUARD + tid] = 0.0f;                              // LDS row 0
        xs[GUARD + 57 * PW + tid] = 0.0f;                    // LDS row 57
    }
    if (tid < 224) {                                         // pad cols 56..59
        const int rr = 1 + (tid >> 2);
        xs[GUARD + rr * PW + 56 + (tid & 3)] = 0.0f;
    }
    if (tid < HW / 32) keepw[tid] = 0u;
    if (tid == 255) s_cnt = 0;

    // ---- stage interior: one float4 per quad, aligned ds_write_b128 ----
    for (int t = tid; t < NQ; t += NT) {
        const float4 v = reinterpret_cast<const float4*>(xp)[t];
        const int y = t / 14;                // quad row
        const int m = t - 14 * y;            // quad within row
        *reinterpret_cast<float4*>(&xs[GUARD + (y + 1) * PW + 4 * m]) = v;
    }
    __syncthreads();                                         // B1

    // ---- f32 conv, 4 outputs per quad, vector LDS reads ----
    const float wa[3] = { w00, w10, w20 };
    const float wb[3] = { w01, w11, w21 };
    const float wc[3] = { w02, w12, w22 };

    unsigned int k32[16];
    unsigned int mx = 0u;
    #pragma unroll
    for (int kq = 0; kq < 4; ++kq) {
        const int q = tid + kq * NT;
        #pragma unroll
        for (int j = 0; j < 4; ++j) k32[kq * 4 + j] = 0u;
        if (q < NQ) {
            const int r = q / 14;
            const int m = q - 14 * r;
            const int base = GUARD + r * PW + 4 * m;   // LDS row r-1+1 = r
            float acc0 = bv, acc1 = bv, acc2 = bv, acc3 = bv;
            #pragma unroll
            for (int dr = 0; dr < 3; ++dr) {
                const int b = base + dr * PW;
                const float2 vl = *reinterpret_cast<const float2*>(&xs[b - 2]); // cols c-2,c-1
                const float4 vm = *reinterpret_cast<const float4*>(&xs[b]);     // cols c..c+3
                const float  vr = xs[b + 4];                                    // col  c+4
                acc0 = fmaf(wa[dr], vl.y, acc0);
                acc0 = fmaf(wb[dr], vm.x, acc0);
                acc0 = fmaf(wc[dr], vm.y, acc0);
                acc1 = fmaf(wa[dr], vm.x, acc1);
                acc1 = fmaf(wb[dr], vm.y, acc1);
                acc1 = fmaf(wc[dr], vm.z, acc1);
                acc2 = fmaf(wa[dr], vm.y, acc2);
                acc2 = fmaf(wb[dr], vm.z, acc2);
                acc2 = fmaf(wc[dr], vm.w, acc2);
                acc3 = fmaf(wa[dr], vm.z, acc3);
                acc3 = fmaf(wb[dr], vm.w, acc3);
                acc3 = fmaf(wc[dr], vr,   acc3);
            }
            const float accs[4] = { acc0, acc1, acc2, acc3 };
            #pragma unroll
            for (int j = 0; j < 4; ++j) {
                const unsigned int bb = __float_as_uint(accs[j]);
                const unsigned int key = ((int)bb < 0) ? ~bb : (bb | 0x80000000u);
                k32[kq * 4 + j] = key;
                mx = (key > mx) ? key : mx;
            }
        }
    }
    smax[tid] = mx;
    __syncthreads();                                         // B2

    // ---- wave 0: binary search on hi-16 bits, ballot+popcount ----
    if (tid < 64) {
        const unsigned int m0 = smax[tid]       >> 16;
        const unsigned int m1 = smax[tid + 64]  >> 16;
        const unsigned int m2 = smax[tid + 128] >> 16;
        const unsigned int m3 = smax[tid + 192] >> 16;
        unsigned int lo = 0u, hi = 65536u;   // cnt(>=lo) >= 30 > cnt(>=hi)
        while (hi - lo > 1u) {
            const unsigned int mid = (lo + hi) >> 1;
            const int c = (m0 >= mid) + (m1 >= mid) + (m2 >= mid) + (m3 >= mid);
            const unsigned long long b0 = __ballot(c & 1);
            const unsigned long long b1 = __ballot(c & 2);
            const unsigned long long b2 = __ballot(c & 4);
            const int cnt = __popcll(b0) + 2 * __popcll(b1) + 4 * __popcll(b2);
            if (cnt >= KSEL) { lo = mid; if (cnt <= 48) break; }
            else hi = mid;
        }
        if (tid == 0) s_T16 = lo;
    }
    __syncthreads();                                         // B3

    // ---- widen cut by absolute margin 1e-4 in float domain ----
    const unsigned int binkey = s_T16 << 16;
    const float Tf = (binkey & 0x80000000u)
                         ? __uint_as_float(binkey ^ 0x80000000u)
                         : __uint_as_float(~binkey);
    const float Tm = Tf - 1e-4f;
    const unsigned int tb    = __float_as_uint(Tm);
    const unsigned int TmKey = ((int)tb < 0) ? ~tb : (tb | 0x80000000u);

    // ---- gather candidate indices ----
    #pragma unroll
    for (int kq = 0; kq < 4; ++kq) {
        const int q = tid + kq * NT;
        if (q < NQ) {
            #pragma unroll
            for (int j = 0; j < 4; ++j) {
                if (k32[kq * 4 + j] >= TmKey) {
                    const int slot = atomicAdd(&s_cnt, 1);
                    if (slot < CAP) c_idx[slot] = 4 * q + j;
                }
            }
        }
    }
    __syncthreads();                                         // B4

    // ---- f64 recompute for candidates (np-matching fma order) ----
    const int E = (s_cnt < CAP) ? s_cnt : CAP;
    if (tid < E) {
        const int i = c_idx[tid];
        const int y = i / W;
        const int p = GUARD + (y + 1) * PW + (i - y * W);
        double s = (double)bv;
        s = fma((double)w00, (double)xs[p - PW - 1], s);
        s = fma((double)w01, (double)xs[p - PW    ], s);
        s = fma((double)w02, (double)xs[p - PW + 1], s);
        s = fma((double)w10, (double)xs[p - 1],      s);
        s = fma((double)w11, (double)xs[p],          s);
        s = fma((double)w12, (double)xs[p + 1],      s);
        s = fma((double)w20, (double)xs[p + PW - 1], s);
        s = fma((double)w21, (double)xs[p + PW    ], s);
        s = fma((double)w22, (double)xs[p + PW + 1], s);
        c_sd[tid] = s;
    }
    __syncthreads();                                         // B5

    // ---- exact rank among candidates: (s64 desc, idx asc); keep rank<K ----
    if (tid < E) {
        const double se = c_sd[tid];
        const int    ei = c_idx[tid];
        int rank = 0;
        for (int j = 0; j < E; ++j) {
            const double sj = c_sd[j];
            const int    ji = c_idx[j];
            rank += (sj > se) || (sj == se && ji < ei);
        }
        if (rank < KSEL) atomicOr(&keepw[ei >> 5], 1u << (ei & 31));
    }
    __syncthreads();                                         // B6

    // ---- output: aligned LDS quad read x keep bits -> dwordx4 store ----
    #pragma unroll
    for (int kq = 0; kq < 4; ++kq) {
        const int q = tid + kq * NT;
        if (q < NQ) {
            const int r = q / 14;
            const int m = q - 14 * r;
            const int i = 4 * q;
            const float4 xv = *reinterpret_cast<const float4*>(
                &xs[GUARD + (r + 1) * PW + 4 * m]);
            const unsigned int wbits = keepw[i >> 5] >> (i & 31);
            float4 v;
            v.x = (wbits & 1u) ? xv.x : 0.0f;
            v.y = (wbits & 2u) ? xv.y : 0.0f;
            v.z = (wbits & 4u) ? xv.z : 0.0f;
            v.w = (wbits & 8u) ? xv.w : 0.0f;
            reinterpret_cast<float4*>(op)[q] = v;
        }
    }
}

extern "C" void kernel_launch(void* const* d_in, const int* in_sizes, int n_in,
                              void* d_out, int out_size, void* d_ws, size_t ws_size,
                              hipStream_t stream) {
    const float* x  = (const float*)d_in[0];
    const float* w  = (const float*)d_in[1];
    const float* b  = (const float*)d_in[2];
    float* out      = (float*)d_out;

    const int C  = in_sizes[2];            // 384
    const int BC = in_sizes[0] / HW;       // b*c = 12288

    topk_spatial_kernel<<<BC, NT, 0, stream>>>(x, w, b, out, C);
}

// Round 6
// 103.899 us; speedup vs baseline: 2.4475x; 1.0862x over previous
//
#include <hip/hip_runtime.h>

#define NT 256
#define W 56
#define HW 3136            // 56*56
#define PW 60              // padded row stride (floats)
#define GUARD 64           // zero guard before row 0
#define PAD_SZ (GUARD + 58*PW)   // 64 + 3480 = 3544 floats
#define KSEL 30
#define NQ (HW/4)          // 784 quads
#define CAP 160
#define ACT 196            // 14 quad-cols x 14 row-groups

typedef float v2f __attribute__((ext_vector_type(2)));

__device__ __forceinline__ v2f vfma(v2f a, v2f b, v2f c) {
#if __has_builtin(__builtin_elementwise_fma)
    return __builtin_elementwise_fma(a, b, c);
#else
    v2f r; r.x = fmaf(a.x, b.x, c.x); r.y = fmaf(a.y, b.y, c.y); return r;
#endif
}

__global__ __launch_bounds__(NT, 4) void topk_spatial_kernel(
    const float* __restrict__ x,
    const float* __restrict__ wgt,
    const float* __restrict__ bias,
    float* __restrict__ out,
    int C)
{
    // xs[GUARD + (y+1)*PW + col] = x(y, col); cols 56..59 zero, LDS rows 0 and
    // 57 zero, xs[0..GUARD-1] zero -> all halo reads land on zeros, unbranched.
    __shared__ float        xs[PAD_SZ];
    __shared__ unsigned int smax[NT];
    __shared__ int          c_idx[CAP];
    __shared__ double       c_sd[CAP];
    __shared__ unsigned int keepw[HW / 32];   // 98 words
    __shared__ unsigned int s_T16;
    __shared__ int s_cnt;

    const int tid = threadIdx.x;
    const int bc  = blockIdx.x;              // b*C + c
    const int ci  = bc % C;

    const float* xp = x   + (size_t)bc * HW;
    float*       op = out + (size_t)bc * HW;

    const float* wpt = wgt + (size_t)ci * 9;
    const float wk[3][3] = { { wpt[0], wpt[1], wpt[2] },
                             { wpt[3], wpt[4], wpt[5] },
                             { wpt[6], wpt[7], wpt[8] } };
    const float bv = bias[ci];

    // ---- zero init (disjoint regions; interior overwritten by staging) ----
    if (tid < GUARD) xs[tid] = 0.0f;                         // guard
    if (tid < PW) {
        xs[GUARD + tid] = 0.0f;                              // LDS row 0
        xs[GUARD + 57 * PW + tid] = 0.0f;                    // LDS row 57
    }
    if (tid < 224) {                                         // pad cols 56..59
        const int rr = 1 + (tid >> 2);
        xs[GUARD + rr * PW + 56 + (tid & 3)] = 0.0f;
    }
    if (tid < HW / 32) keepw[tid] = 0u;
    if (tid == 255) s_cnt = 0;

    // ---- stage interior: one aligned ds_write_b128 per quad ----
    for (int t = tid; t < NQ; t += NT) {
        const float4 v = reinterpret_cast<const float4*>(xp)[t];
        const int y = t / 14;
        const int m = t - 14 * y;
        *reinterpret_cast<float4*>(&xs[GUARD + (y + 1) * PW + 4 * m]) = v;
    }
    __syncthreads();                                         // B1

    // ---- conv: each active thread owns a 4x4 output tile; 6-row sliding
    //      window, each LDS row read ONCE (float2+float4+float) ----
    const bool active = (tid < ACT);
    const int  m_ = tid % 14;          // quad col
    const int  g_ = tid / 14;          // row group (4 rows)

    unsigned int k32[16];
    float4 xm[4];
    unsigned int mx = 0u;

    if (active) {
        v2f accL[4], accH[4];
        #pragma unroll
        for (int k = 0; k < 4; ++k) { accL[k] = v2f{bv, bv}; accH[k] = v2f{bv, bv}; }

        const int base0 = GUARD + (4 * g_) * PW + 4 * m_;   // LDS row 4g+dr
        #pragma unroll
        for (int dr = 0; dr < 6; ++dr) {
            const int b = base0 + dr * PW;
            const float2 vl = *reinterpret_cast<const float2*>(&xs[b - 2]);
            const float4 vm = *reinterpret_cast<const float4*>(&xs[b]);
            const float  vr = xs[b + 4];
            const v2f p0 = { vl.y, vm.x };
            const v2f p1 = { vm.x, vm.y };
            const v2f p2 = { vm.y, vm.z };
            const v2f p3 = { vm.z, vm.w };
            const v2f p4 = { vm.w, vr   };
            #pragma unroll
            for (int k = 0; k < 4; ++k) {
                const int kr = dr - k;                       // kernel row
                if (kr >= 0 && kr < 3) {
                    const v2f wA = { wk[kr][0], wk[kr][0] };
                    const v2f wB = { wk[kr][1], wk[kr][1] };
                    const v2f wC = { wk[kr][2], wk[kr][2] };
                    accL[k] = vfma(wA, p0, accL[k]);
                    accL[k] = vfma(wB, p1, accL[k]);
                    accL[k] = vfma(wC, p2, accL[k]);
                    accH[k] = vfma(wA, p2, accH[k]);
                    accH[k] = vfma(wB, p3, accH[k]);
                    accH[k] = vfma(wC, p4, accH[k]);
                }
            }
            if (dr >= 1 && dr <= 4) xm[dr - 1] = vm;         // this tile's x
        }

        #pragma unroll
        for (int k = 0; k < 4; ++k) {
            const float sv[4] = { accL[k].x, accL[k].y, accH[k].x, accH[k].y };
            #pragma unroll
            for (int j = 0; j < 4; ++j) {
                const unsigned int bb = __float_as_uint(sv[j]);
                const unsigned int key = ((int)bb < 0) ? ~bb : (bb | 0x80000000u);
                k32[k * 4 + j] = key;
                mx = (key > mx) ? key : mx;
            }
        }
    } else {
        #pragma unroll
        for (int kk = 0; kk < 16; ++kk) k32[kk] = 0u;
    }

    smax[tid] = mx;
    __syncthreads();                                         // B2

    // ---- wave 0: binary search on hi-16 key bits, ballot+popcount ----
    if (tid < 64) {
        const unsigned int m0 = smax[tid]       >> 16;
        const unsigned int m1 = smax[tid + 64]  >> 16;
        const unsigned int m2 = smax[tid + 128] >> 16;
        const unsigned int m3 = smax[tid + 192] >> 16;
        unsigned int lo = 0u, hi = 65536u;   // cnt(>=lo) >= 30 > cnt(>=hi)
        while (hi - lo > 1u) {
            const unsigned int mid = (lo + hi) >> 1;
            const int c = (m0 >= mid) + (m1 >= mid) + (m2 >= mid) + (m3 >= mid);
            const unsigned long long b0 = __ballot(c & 1);
            const unsigned long long b1 = __ballot(c & 2);
            const unsigned long long b2 = __ballot(c & 4);
            const int cnt = __popcll(b0) + 2 * __popcll(b1) + 4 * __popcll(b2);
            if (cnt >= KSEL) { lo = mid; if (cnt <= 48) break; }
            else hi = mid;
        }
        if (tid == 0) s_T16 = lo;
    }
    __syncthreads();                                         // B3

    // ---- widen cut by absolute margin 1e-4 in float domain ----
    const unsigned int binkey = s_T16 << 16;
    const float Tf = (binkey & 0x80000000u)
                         ? __uint_as_float(binkey ^ 0x80000000u)
                         : __uint_as_float(~binkey);
    const float Tm = Tf - 1e-4f;
    const unsigned int tb    = __float_as_uint(Tm);
    const unsigned int TmKey = ((int)tb < 0) ? ~tb : (tb | 0x80000000u);

    // ---- gather candidate indices ----
    if (active) {
        #pragma unroll
        for (int kk = 0; kk < 16; ++kk) {
            if (k32[kk] >= TmKey) {
                const int slot = atomicAdd(&s_cnt, 1);
                if (slot < CAP)
                    c_idx[slot] = (4 * g_ + (kk >> 2)) * W + 4 * m_ + (kk & 3);
            }
        }
    }
    __syncthreads();                                         // B4

    // ---- f64 recompute for candidates (np-matching fma order) ----
    const int E = (s_cnt < CAP) ? s_cnt : CAP;
    if (tid < E) {
        const int i = c_idx[tid];
        const int y = i / W;
        const int p = GUARD + (y + 1) * PW + (i - y * W);
        double s = (double)bv;
        s = fma((double)wk[0][0], (double)xs[p - PW - 1], s);
        s = fma((double)wk[0][1], (double)xs[p - PW    ], s);
        s = fma((double)wk[0][2], (double)xs[p - PW + 1], s);
        s = fma((double)wk[1][0], (double)xs[p - 1],      s);
        s = fma((double)wk[1][1], (double)xs[p],          s);
        s = fma((double)wk[1][2], (double)xs[p + 1],      s);
        s = fma((double)wk[2][0], (double)xs[p + PW - 1], s);
        s = fma((double)wk[2][1], (double)xs[p + PW    ], s);
        s = fma((double)wk[2][2], (double)xs[p + PW + 1], s);
        c_sd[tid] = s;
    }
    __syncthreads();                                         // B5

    // ---- exact rank among candidates: (s64 desc, idx asc); keep rank<K ----
    if (tid < E) {
        const double se = c_sd[tid];
        const int    ei = c_idx[tid];
        int rank = 0;
        for (int j = 0; j < E; ++j) {
            const double sj = c_sd[j];
            const int    ji = c_idx[j];
            rank += (sj > se) || (sj == se && ji < ei);
        }
        if (rank < KSEL) atomicOr(&keepw[ei >> 5], 1u << (ei & 31));
    }
    __syncthreads();                                         // B6

    // ---- output straight from registers (no LDS x re-read) ----
    if (active) {
        #pragma unroll
        for (int k = 0; k < 4; ++k) {
            const int ib = (4 * g_ + k) * W + 4 * m_;        // ib % 4 == 0
            const unsigned int bits = keepw[ib >> 5] >> (ib & 31);
            float4 v = xm[k];
            v.x = (bits & 1u) ? v.x : 0.0f;
            v.y = (bits & 2u) ? v.y : 0.0f;
            v.z = (bits & 4u) ? v.z : 0.0f;
            v.w = (bits & 8u) ? v.w : 0.0f;
            *reinterpret_cast<float4*>(&op[ib]) = v;
        }
    }
}

extern "C" void kernel_launch(void* const* d_in, const int* in_sizes, int n_in,
                              void* d_out, int out_size, void* d_ws, size_t ws_size,
                              hipStream_t stream) {
    const float* x  = (const float*)d_in[0];
    const float* w  = (const float*)d_in[1];
    const float* b  = (const float*)d_in[2];
    float* out      = (float*)d_out;

    const int C  = in_sizes[2];            // 384
    const int BC = in_sizes[0] / HW;       // b*c = 12288

    topk_spatial_kernel<<<BC, NT, 0, stream>>>(x, w, b, out, C);
}

// Round 7
// 96.762 us; speedup vs baseline: 2.6280x; 1.0738x over previous
//
#include <hip/hip_runtime.h>

#define NT 256
#define W 56
#define HW 3136            // 56*56
#define PW 60              // padded row stride (floats)
#define GUARD 64           // zero guard before row 0
#define PAD_SZ (GUARD + 58*PW)   // 64 + 3480 = 3544 floats
#define KSEL 30
#define NQ (HW/4)          // 784 quads
#define CAP 160
#define ACT 196            // 14 quad-cols x 14 row-groups

typedef float v2f __attribute__((ext_vector_type(2)));

__device__ __forceinline__ v2f vfma(v2f a, v2f b, v2f c) {
#if __has_builtin(__builtin_elementwise_fma)
    return __builtin_elementwise_fma(a, b, c);
#else
    v2f r; r.x = fmaf(a.x, b.x, c.x); r.y = fmaf(a.y, b.y, c.y); return r;
#endif
}

__global__ __launch_bounds__(NT, 8) void topk_spatial_kernel(
    const float* __restrict__ x,
    const float* __restrict__ wgt,
    const float* __restrict__ bias,
    float* __restrict__ out,
    int C)
{
    // xs[GUARD + (y+1)*PW + col] = x(y, col); cols 56..59 zero, LDS rows 0 and
    // 57 zero, xs[0..GUARD-1] zero -> all halo reads land on zeros, unbranched.
    __shared__ float        xs[PAD_SZ];
    __shared__ unsigned int smax[NT];
    __shared__ int          c_idx[CAP];
    __shared__ double       c_sd[CAP];
    __shared__ unsigned int keepw[HW / 32];   // 98 words
    __shared__ unsigned int s_T16;
    __shared__ int s_cnt;

    const int tid = threadIdx.x;
    const int bc  = blockIdx.x;              // b*C + c
    const int ci  = bc % C;

    const float* xp = x   + (size_t)bc * HW;
    float*       op = out + (size_t)bc * HW;

    const float* wpt = wgt + (size_t)ci * 9;
    const float wk[3][3] = { { wpt[0], wpt[1], wpt[2] },
                             { wpt[3], wpt[4], wpt[5] },
                             { wpt[6], wpt[7], wpt[8] } };
    const float bv = bias[ci];

    // ---- zero init (disjoint regions; interior overwritten by staging) ----
    if (tid < GUARD) xs[tid] = 0.0f;                         // guard
    if (tid < PW) {
        xs[GUARD + tid] = 0.0f;                              // LDS row 0
        xs[GUARD + 57 * PW + tid] = 0.0f;                    // LDS row 57
    }
    if (tid < 224) {                                         // pad cols 56..59
        const int rr = 1 + (tid >> 2);
        xs[GUARD + rr * PW + 56 + (tid & 3)] = 0.0f;
    }
    if (tid < HW / 32) keepw[tid] = 0u;
    if (tid == 255) s_cnt = 0;

    // ---- stage interior: one aligned ds_write_b128 per quad ----
    for (int t = tid; t < NQ; t += NT) {
        const float4 v = reinterpret_cast<const float4*>(xp)[t];
        const int y = t / 14;
        const int m = t - 14 * y;
        *reinterpret_cast<float4*>(&xs[GUARD + (y + 1) * PW + 4 * m]) = v;
    }
    __syncthreads();                                         // B1

    // ---- conv: each active thread owns a 4x4 output tile; 6-row sliding
    //      window, each LDS row read ONCE (float2+float4+float) ----
    const bool active = (tid < ACT);
    const int  m_ = tid % 14;          // quad col
    const int  g_ = tid / 14;          // row group (4 rows)

    unsigned int k32[16];
    float4 xm[4];
    unsigned int mx = 0u;

    if (active) {
        v2f accL[4], accH[4];
        #pragma unroll
        for (int k = 0; k < 4; ++k) { accL[k] = v2f{bv, bv}; accH[k] = v2f{bv, bv}; }

        const int base0 = GUARD + (4 * g_) * PW + 4 * m_;   // LDS row 4g+dr
        #pragma unroll
        for (int dr = 0; dr < 6; ++dr) {
            const int b = base0 + dr * PW;
            const float2 vl = *reinterpret_cast<const float2*>(&xs[b - 2]);
            const float4 vm = *reinterpret_cast<const float4*>(&xs[b]);
            const float  vr = xs[b + 4];
            const v2f p0 = { vl.y, vm.x };
            const v2f p1 = { vm.x, vm.y };
            const v2f p2 = { vm.y, vm.z };
            const v2f p3 = { vm.z, vm.w };
            const v2f p4 = { vm.w, vr   };
            #pragma unroll
            for (int k = 0; k < 4; ++k) {
                const int kr = dr - k;                       // kernel row
                if (kr >= 0 && kr < 3) {
                    const v2f wA = { wk[kr][0], wk[kr][0] };
                    const v2f wB = { wk[kr][1], wk[kr][1] };
                    const v2f wC = { wk[kr][2], wk[kr][2] };
                    accL[k] = vfma(wA, p0, accL[k]);
                    accL[k] = vfma(wB, p1, accL[k]);
                    accL[k] = vfma(wC, p2, accL[k]);
                    accH[k] = vfma(wA, p2, accH[k]);
                    accH[k] = vfma(wB, p3, accH[k]);
                    accH[k] = vfma(wC, p4, accH[k]);
                }
            }
            if (dr >= 1 && dr <= 4) xm[dr - 1] = vm;         // this tile's x
        }

        #pragma unroll
        for (int k = 0; k < 4; ++k) {
            const float sv[4] = { accL[k].x, accL[k].y, accH[k].x, accH[k].y };
            #pragma unroll
            for (int j = 0; j < 4; ++j) {
                const unsigned int bb = __float_as_uint(sv[j]);
                const unsigned int key = ((int)bb < 0) ? ~bb : (bb | 0x80000000u);
                k32[k * 4 + j] = key;
                mx = (key > mx) ? key : mx;
            }
        }
    } else {
        #pragma unroll
        for (int kk = 0; kk < 16; ++kk) k32[kk] = 0u;
    }

    smax[tid] = mx;
    __syncthreads();                                         // B2

    // ---- wave 0: binary search on hi-16 key bits, ballot+popcount ----
    if (tid < 64) {
        const unsigned int m0 = smax[tid]       >> 16;
        const unsigned int m1 = smax[tid + 64]  >> 16;
        const unsigned int m2 = smax[tid + 128] >> 16;
        const unsigned int m3 = smax[tid + 192] >> 16;
        unsigned int lo = 0u, hi = 65536u;   // cnt(>=lo) >= 30 > cnt(>=hi)
        while (hi - lo > 1u) {
            const unsigned int mid = (lo + hi) >> 1;
            const int c = (m0 >= mid) + (m1 >= mid) + (m2 >= mid) + (m3 >= mid);
            const unsigned long long b0 = __ballot(c & 1);
            const unsigned long long b1 = __ballot(c & 2);
            const unsigned long long b2 = __ballot(c & 4);
            const int cnt = __popcll(b0) + 2 * __popcll(b1) + 4 * __popcll(b2);
            if (cnt >= KSEL) { lo = mid; if (cnt <= 48) break; }
            else hi = mid;
        }
        if (tid == 0) s_T16 = lo;
    }
    __syncthreads();                                         // B3

    // ---- widen cut by absolute margin 1e-4 in float domain ----
    const unsigned int binkey = s_T16 << 16;
    const float Tf = (binkey & 0x80000000u)
                         ? __uint_as_float(binkey ^ 0x80000000u)
                         : __uint_as_float(~binkey);
    const float Tm = Tf - 1e-4f;
    const unsigned int tb    = __float_as_uint(Tm);
    const unsigned int TmKey = ((int)tb < 0) ? ~tb : (tb | 0x80000000u);

    // ---- gather candidate indices ----
    if (active) {
        #pragma unroll
        for (int kk = 0; kk < 16; ++kk) {
            if (k32[kk] >= TmKey) {
                const int slot = atomicAdd(&s_cnt, 1);
                if (slot < CAP)
                    c_idx[slot] = (4 * g_ + (kk >> 2)) * W + 4 * m_ + (kk & 3);
            }
        }
    }
    __syncthreads();                                         // B4

    // ---- f64 recompute for candidates (np-matching fma order) ----
    const int E = (s_cnt < CAP) ? s_cnt : CAP;
    if (tid < E) {
        const int i = c_idx[tid];
        const int y = i / W;
        const int p = GUARD + (y + 1) * PW + (i - y * W);
        double s = (double)bv;
        s = fma((double)wk[0][0], (double)xs[p - PW - 1], s);
        s = fma((double)wk[0][1], (double)xs[p - PW    ], s);
        s = fma((double)wk[0][2], (double)xs[p - PW + 1], s);
        s = fma((double)wk[1][0], (double)xs[p - 1],      s);
        s = fma((double)wk[1][1], (double)xs[p],          s);
        s = fma((double)wk[1][2], (double)xs[p + 1],      s);
        s = fma((double)wk[2][0], (double)xs[p + PW - 1], s);
        s = fma((double)wk[2][1], (double)xs[p + PW    ], s);
        s = fma((double)wk[2][2], (double)xs[p + PW + 1], s);
        c_sd[tid] = s;
    }
    __syncthreads();                                         // B5

    // ---- exact rank among candidates: (s64 desc, idx asc); keep rank<K ----
    if (tid < E) {
        const double se = c_sd[tid];
        const int    ei = c_idx[tid];
        int rank = 0;
        for (int j = 0; j < E; ++j) {
            const double sj = c_sd[j];
            const int    ji = c_idx[j];
            rank += (sj > se) || (sj == se && ji < ei);
        }
        if (rank < KSEL) atomicOr(&keepw[ei >> 5], 1u << (ei & 31));
    }
    __syncthreads();                                         // B6

    // ---- output straight from registers (no LDS x re-read) ----
    if (active) {
        #pragma unroll
        for (int k = 0; k < 4; ++k) {
            const int ib = (4 * g_ + k) * W + 4 * m_;        // ib % 4 == 0
            const unsigned int bits = keepw[ib >> 5] >> (ib & 31);
            float4 v = xm[k];
            v.x = (bits & 1u) ? v.x : 0.0f;
            v.y = (bits & 2u) ? v.y : 0.0f;
            v.z = (bits & 4u) ? v.z : 0.0f;
            v.w = (bits & 8u) ? v.w : 0.0f;
            *reinterpret_cast<float4*>(&op[ib]) = v;
        }
    }
}

extern "C" void kernel_launch(void* const* d_in, const int* in_sizes, int n_in,
                              void* d_out, int out_size, void* d_ws, size_t ws_size,
                              hipStream_t stream) {
    const float* x  = (const float*)d_in[0];
    const float* w  = (const float*)d_in[1];
    const float* b  = (const float*)d_in[2];
    float* out      = (float*)d_out;

    const int C  = in_sizes[2];            // 384
    const int BC = in_sizes[0] / HW;       // b*c = 12288

    topk_spatial_kernel<<<BC, NT, 0, stream>>>(x, w, b, out, C);
}